// Round 1
// baseline (133.290 us; speedup 1.0000x reference)
//
#include <hip/hip_runtime.h>

// Problem constants (from reference setup_inputs): [T+1, B] = [1024, 4096] fp32
#define T1     1024
#define T      1023
#define B      4096
#define LOGB   12
#define CHUNK  16
#define NCHUNK 64    // ceil(T / CHUNK); chunk c covers t in [16c, min(16c+16, 1023))

#define GAMMA     0.99f
#define TD_LAMBDA 0.95f

// Phase 1: per (chunk, column), compose the chunk's affine steps
// adv[t] = a_t + b_t * adv[t+1]  into  adv[s] = A + Bf * adv[e].
__global__ __launch_bounds__(256) void k_compose(
    const float* __restrict__ tv, const float* __restrict__ rew,
    const int* __restrict__ st, const float* __restrict__ disc,
    float* __restrict__ Ac, float* __restrict__ Bc)
{
    int tid = blockIdx.x * blockDim.x + threadIdx.x;
    int b = tid & (B - 1);
    int c = tid >> LOGB;
    int s = c * CHUNK;
    int e = min(s + CHUNK, T);

    float A = 0.f, Bf = 1.f;
    float tv_next = tv[(size_t)e * B + b];   // tv[t+1] for the first (highest-t) step
    for (int t = e - 1; t >= s; --t) {
        size_t idx  = (size_t)t * B + b;
        size_t idx1 = idx + B;
        float d1    = disc[idx1] * GAMMA;
        float tv_t  = tv[idx];
        float delta = rew[idx1] + d1 * tv_next - tv_t;
        float wd    = d1 * TD_LAMBDA;
        float nl    = (st[idx] == 2) ? 0.f : 1.f;
        float a  = nl * delta;
        float bb = nl * wd;
        A  = fmaf(bb, A, a);    // compose: new_adv[s..] = a + bb * (previous composition)
        Bf = bb * Bf;
        tv_next = tv_t;
    }
    Ac[tid] = A;     // layout [c][b] == tid
    Bc[tid] = Bf;
}

// Phase 2: sequential scan over chunk boundaries (per column).
// R[c][b] = adv at t = chunk_end(c) (the value entering chunk c from the right).
__global__ __launch_bounds__(256) void k_scan(
    const float* __restrict__ Ac, const float* __restrict__ Bc,
    float* __restrict__ R)
{
    int b = blockIdx.x * blockDim.x + threadIdx.x;   // 0..B-1
    float adv = 0.f;                                  // adv[T] init = 0
    for (int c = NCHUNK - 1; c >= 0; --c) {
        int i = c * B + b;
        R[i] = adv;
        adv = fmaf(Bc[i], adv, Ac[i]);
    }
}

// Phase 3: replay each chunk with its known right-boundary adv; emit loss.
__global__ __launch_bounds__(256) void k_replay(
    const float* __restrict__ value, const float* __restrict__ tv,
    const float* __restrict__ rew, const int* __restrict__ st,
    const float* __restrict__ disc, const float* __restrict__ R,
    float* __restrict__ out)
{
    int tid = blockIdx.x * blockDim.x + threadIdx.x;
    int b = tid & (B - 1);
    int c = tid >> LOGB;
    int s = c * CHUNK;
    int e = min(s + CHUNK, T);

    float adv = R[tid];
    float tv_next = tv[(size_t)e * B + b];
    if (c == NCHUNK - 1) {
        // tensor_extend_zero: last output row is zeros (d_out is poisoned, must write)
        out[(size_t)T * B + b] = 0.f;
    }
    for (int t = e - 1; t >= s; --t) {
        size_t idx  = (size_t)t * B + b;
        size_t idx1 = idx + B;
        float d1    = disc[idx1] * GAMMA;
        float tv_t  = tv[idx];
        float delta = rew[idx1] + d1 * tv_next - tv_t;
        float wd    = d1 * TD_LAMBDA;
        float nl    = (st[idx] == 2) ? 0.f : 1.f;
        adv = nl * fmaf(wd, adv, delta);
        float td = adv + tv_t - value[idx];
        out[idx] = td * td;
        tv_next = tv_t;
    }
}

extern "C" void kernel_launch(void* const* d_in, const int* in_sizes, int n_in,
                              void* d_out, int out_size, void* d_ws, size_t ws_size,
                              hipStream_t stream) {
    // setup_inputs order: value, target_value, reward, step_type, discount
    const float* value = (const float*)d_in[0];
    const float* tv    = (const float*)d_in[1];
    const float* rew   = (const float*)d_in[2];
    const int*   st    = (const int*)d_in[3];
    const float* disc  = (const float*)d_in[4];
    float* out = (float*)d_out;

    // Workspace: 3 arrays of NCHUNK*B floats = 3 MiB total
    float* Ac = (float*)d_ws;
    float* Bc = Ac + (size_t)NCHUNK * B;
    float* R  = Bc + (size_t)NCHUNK * B;

    k_compose<<<(NCHUNK * B) / 256, 256, 0, stream>>>(tv, rew, st, disc, Ac, Bc);
    k_scan<<<B / 256, 256, 0, stream>>>(Ac, Bc, R);
    k_replay<<<(NCHUNK * B) / 256, 256, 0, stream>>>(value, tv, rew, st, disc, R, out);
}